// Round 13
// baseline (395.040 us; speedup 1.0000x reference)
//
#include <hip/hip_runtime.h>
#include <stdint.h>

#define NDET 8192
#define ROWCAP 128      // max stored edges per row (j>i). P(overflow) ~ 0 for this data.
#define BATCH 64
#define NBATCH (NDET / BATCH)   // 128

// ---------------- ws layout (bytes) ----------------
// 0        u32    cnt  [8192]     32768
// 32768    u32    alab [8192]     32768
// 65536    u16    sched[8192]     16384
// 81920    int    depth[128]        512
// 131072   u16    edges[8192][128] 2097152   (total 2228224 B)

// Extract edge e (compile-time constant after unroll) from the two uint4 regs.
#define EW(e) ((e) < 8 ? (((e) >> 1) == 0 ? pa.x : ((e) >> 1) == 1 ? pa.y : ((e) >> 1) == 2 ? pa.z : pa.w) \
                       : ((((e) - 8) >> 1) == 0 ? pb.x : (((e) - 8) >> 1) == 1 ? pb.y : (((e) - 8) >> 1) == 2 ? pb.z : pb.w))
#define EDGE(e) ((int)((EW(e) >> (((e) & 1) * 16)) & 0xFFFFu))

// Corner-form + area computed on the fly from raw cxcywh (bit-identical to the
// reference expressions; contract off so no FMA fusion changes rounding).
__device__ __forceinline__ void box_corners(const float4 b, float& x1, float& y1,
                                            float& x2, float& y2, float& ar) {
  #pragma clang fp contract(off)
  x1 = b.x - 0.5f * b.z; y1 = b.y - 0.5f * b.w;
  x2 = b.x + 0.5f * b.z; y2 = b.y + 0.5f * b.w;
  ar = (x2 - x1) * (y2 - y1);
}

// One wave handles rows (w) and (8191-w): balanced upper-triangle scan.
__global__ __launch_bounds__(256) void k_edges(const float4* __restrict__ bb,
    uint32_t* __restrict__ cnt, uint16_t* __restrict__ edges) {
  #pragma clang fp contract(off)
  int wid  = (blockIdx.x * 256 + threadIdx.x) >> 6;   // 0..4095
  int lane = threadIdx.x & 63;
  for (int half = 0; half < 2; ++half) {
    int r = (half == 0) ? wid : (NDET - 1 - wid);
    float ix1, iy1, ix2, iy2, ai;
    box_corners(bb[r], ix1, iy1, ix2, iy2, ai);
    uint16_t* erow = edges + (size_t)r * ROWCAP;
    int cnt_total = 0;
    for (int jc = (r + 1) >> 6; jc < NDET / 64; ++jc) {
      int j = (jc << 6) + lane;
      bool pred = false;
      if (j > r) {
        float jx1, jy1, jx2, jy2, aj;
        box_corners(bb[j], jx1, jy1, jx2, jy2, aj);
        float ltx = fmaxf(ix1, jx1), lty = fmaxf(iy1, jy1);
        float rbx = fminf(ix2, jx2), rby = fminf(iy2, jy2);
        float iw = fmaxf(rbx - ltx, 0.0f), ih = fmaxf(rby - lty, 0.0f);
        float inter = iw * ih;
        float uni = ai + aj - inter;     // > 0 always (w,h >= 10)
        float iou = inter / uni;         // IEEE div, matches reference
        pred = iou > 0.1f;
      }
      unsigned long long m = __ballot(pred);
      if (pred) {
        int pos = cnt_total + __popcll(m & ((1ull << lane) - 1ull));
        if (pos < ROWCAP) erow[pos] = (uint16_t)j;
      }
      cnt_total += __popcll(m);
    }
    if (lane == 0) cnt[r] = (uint32_t)min(cnt_total, ROWCAP);
  }
}

// Static conflict scheduling: one block per batch of 64 consecutive rows.
// Epoch-keyed claims (newer round -> smaller key), >=1 retire/round => k<=64.
__global__ __launch_bounds__(64) void k_sched(const uint16_t* __restrict__ edges,
    const uint32_t* __restrict__ cnt, uint16_t* __restrict__ sched,
    int* __restrict__ depth) {
  __shared__ uint32_t claim[NDET];     // 32 KB
  __shared__ int nleft;
  const int t = threadIdx.x;
  const int r = (blockIdx.x << 6) + t;
  {
    uint4* c4 = reinterpret_cast<uint4*>(claim);
    uint4 ff = make_uint4(0xFFFFFFFFu, 0xFFFFFFFFu, 0xFFFFFFFFu, 0xFFFFFFFFu);
    for (int v = t; v < NDET / 4; v += 64) c4[v] = ff;
  }
  const uint16_t* ep = edges + (size_t)r * ROWCAP;
  uint4 pa = *reinterpret_cast<const uint4*>(ep);
  uint4 pb = *reinterpret_cast<const uint4*>(ep + 8);
  uint32_t deg = cnt[r];
  int js[16];
  #pragma unroll
  for (int e = 0; e < 16; ++e) js[e] = EDGE(e);
  if (t == 0) nleft = 0;
  __syncthreads();
  bool done = (deg == 0u);             // zero-deg rows are exact no-ops, round 0
  if (!done) atomicAdd(&nleft, 1);
  uint32_t myround = 0u;
  int k = 0;
  __syncthreads();                     // nleft final; uniform reads below

  while (nleft > 0) {                  // uniform (read after barrier each iter)
    ++k;
    const uint32_t key = ((uint32_t)(600 - k) << 9) | (uint32_t)t;  // newer round -> smaller
    if (!done) {
      atomicMin(&claim[r], key);
      #pragma unroll
      for (int e = 0; e < 16; ++e)
        if (e < (int)deg) atomicMin(&claim[js[e]], key);
      if (deg > 16u)
        for (int e = 16; e < (int)deg; ++e) atomicMin(&claim[(int)ep[e]], key);
    }
    __syncthreads();
    if (!done) {
      uint32_t cl[16];
      #pragma unroll
      for (int e = 0; e < 16; ++e)
        cl[e] = (e < (int)deg) ? claim[js[e]] : key;   // independent reads, one wait
      bool ready = (claim[r] == key);
      #pragma unroll
      for (int e = 0; e < 16; ++e)
        if (cl[e] != key) ready = false;
      if (ready && deg > 16u)
        for (int e = 16; ready && e < (int)deg; ++e)
          if (claim[(int)ep[e]] != key) ready = false;
      if (ready) { myround = (uint32_t)k; done = true; atomicSub(&nleft, 1); }
    }
    __syncthreads();                   // retires visible; round-k keys now stale
  }
  sched[r] = (uint16_t)myround;
  if (t == 0) depth[blockIdx.x] = k;
}

// SINGLE-WAVE sequential-semantics executor: 128 batches of 64 rows in order;
// within a batch, rows execute at their precomputed round (disjoint per round).
// 64-thread block => __syncthreads degenerates to an intra-wave fence, so the
// per-round cost is ~LDS read latency, not a multi-wave HW barrier.
// Row body = 3 phases (read-all / reg prefix-min / write-all): neighbors are
// strictly ascending => distinct, and the reference reads pre-row values.
__global__ __launch_bounds__(64) void k_scan(const uint16_t* __restrict__ edges,
    const uint32_t* __restrict__ cnt, const uint16_t* __restrict__ sched,
    const int* __restrict__ depth, uint32_t* __restrict__ alab) {
  __shared__ uint16_t a[NDET];         // 16 KB labels
  const int t = threadIdx.x;
  for (int v = t; v < NDET; v += 64) a[v] = (uint16_t)v;

  // prefetch batch 0 (one row per thread)
  const uint16_t* ep = edges + (size_t)t * ROWCAP;
  uint4 pa = *reinterpret_cast<const uint4*>(ep);
  uint4 pb = *reinterpret_cast<const uint4*>(ep + 8);
  uint32_t deg = cnt[t];
  uint32_t rnd = sched[t];
  int dep = depth[0];
  __syncthreads();

  for (int b = 0; b < NBATCH; ++b) {
    const int r = (b << 6) + t;
    uint4 pan = make_uint4(0, 0, 0, 0), pbn = make_uint4(0, 0, 0, 0);
    uint32_t degn = 0u, rndn = 0u;
    int depn = 0;
    if (b < NBATCH - 1) {              // prefetch next batch; waits land after rounds
      const uint16_t* en = edges + (size_t)(r + BATCH) * ROWCAP;
      pan = *reinterpret_cast<const uint4*>(en);
      pbn = *reinterpret_cast<const uint4*>(en + 8);
      degn = cnt[r + BATCH];
      rndn = sched[r + BATCH];
      depn = depth[b + 1];
    }
    for (int k = 1; k <= dep; ++k) {   // uniform loop; no ballot
      if (rnd == (uint32_t)k) {
        int js[16], ls[16];
        #pragma unroll
        for (int e = 0; e < 16; ++e) js[e] = EDGE(e);
        #pragma unroll
        for (int e = 0; e < 16; ++e)   // phase 1: independent reads, one wait
          ls[e] = (e < (int)deg) ? (int)a[js[e]] : 0x7FFFFFFF;
        int cur = (int)a[r];
        #pragma unroll
        for (int e = 0; e < 16; ++e) { // phase 2: register prefix-min
          if (ls[e] < cur) cur = ls[e];
          ls[e] = cur;
        }
        #pragma unroll
        for (int e = 0; e < 16; ++e)   // phase 3: independent writes
          if (e < (int)deg) a[js[e]] = (uint16_t)ls[e];
        if (deg > 16u) {               // rare tail: sequential exact
          for (int e = 16; e < (int)deg; ++e) {
            int j = (int)edges[(size_t)r * ROWCAP + e];
            int aj = (int)a[j];
            if (aj < cur) cur = aj;
            a[j] = (uint16_t)cur;
          }
        }
        a[r] = (uint16_t)cur;
      }
      __syncthreads();                 // single wave: ~lgkmcnt fence
    }
    pa = pan; pb = pbn; deg = degn; rnd = rndn; dep = depn;
  }

  __syncthreads();
  for (int v = t; v < NDET; v += 64) alab[v] = (uint32_t)a[v];
}

// Representative selection entirely in LDS (single block, 1024 threads).
// T1: per-label maxconf bits (conf in [0,1) => non-negative => bit order ==
// float order), later re-zeroed and reused as packed cnt | rank<<16.
// T2: g = min index among members with conf bits == maxconf (exact reference
// tie-break). For cnt==1 the single member IS g, so no minidx table needed.
__global__ __launch_bounds__(1024) void k_fold(const uint32_t* __restrict__ alab,
    const float* __restrict__ conf, int32_t* __restrict__ out) {
  __shared__ uint32_t T1[NDET];        // 32 KB
  __shared__ uint32_t T2[NDET];        // 32 KB
  const int t = threadIdx.x;
  for (int v = t; v < NDET; v += 1024) { T1[v] = 0u; T2[v] = 0xFFFFFFFFu; out[v] = 0; }
  __syncthreads();
  uint32_t L[8], cb[8];
  #pragma unroll
  for (int i = 0; i < 8; ++i) {        // phase A: maxconf per label
    int v = t + i * 1024;
    L[i]  = alab[v];
    cb[i] = __float_as_uint(conf[v]);
    atomicMax(&T1[L[i]], cb[i]);
  }
  __syncthreads();
  #pragma unroll
  for (int i = 0; i < 8; ++i) {        // phase B: g = min idx among argmax-conf
    int v = t + i * 1024;
    if (T1[L[i]] == cb[i]) atomicMin(&T2[L[i]], (uint32_t)v);
  }
  __syncthreads();
  for (int v = t; v < NDET; v += 1024) T1[v] = 0u;   // reuse T1 as cnt|rank
  __syncthreads();
  #pragma unroll
  for (int i = 0; i < 8; ++i) {        // phase C: cnt (lo16) + rank (hi16)
    int v = t + i * 1024;
    atomicAdd(&T1[L[i]], 1u + (((uint32_t)v < T2[L[i]]) ? 0x10000u : 0u));
  }
  __syncthreads();
  for (int Lv = t; Lv < NDET; Lv += 1024) {          // phase D: emit mask
    uint32_t cr = T1[Lv];
    uint32_t c  = cr & 0xFFFFu;
    if (c > 0u) {
      uint32_t idx = (c == 1u) ? T2[Lv] : (cr >> 16);
      out[idx] = 1;                    // idx < NDET always
    }
  }
}

extern "C" void kernel_launch(void* const* d_in, const int* in_sizes, int n_in,
                              void* d_out, int out_size, void* d_ws, size_t ws_size,
                              hipStream_t stream) {
  const float4* bb  = (const float4*)d_in[0];
  const float* conf = (const float*)d_in[1];
  char* ws = (char*)d_ws;
  uint32_t* cnt   = (uint32_t*)(ws + 0);
  uint32_t* alab  = (uint32_t*)(ws + 32768);
  uint16_t* sched = (uint16_t*)(ws + 65536);
  int*      depth = (int*)(ws + 81920);
  uint16_t* edges = (uint16_t*)(ws + 131072);
  int32_t* out = (int32_t*)d_out;

  hipLaunchKernelGGL(k_edges, dim3(1024),   dim3(256),  0, stream, bb, cnt, edges);
  hipLaunchKernelGGL(k_sched, dim3(NBATCH), dim3(64),   0, stream, edges, cnt, sched, depth);
  hipLaunchKernelGGL(k_scan,  dim3(1),      dim3(64),   0, stream, edges, cnt, sched, depth, alab);
  hipLaunchKernelGGL(k_fold,  dim3(1),      dim3(1024), 0, stream, alab, conf, out);
}

// Round 14
// 290.470 us; speedup vs baseline: 1.3600x; 1.3600x over previous
//
#include <hip/hip_runtime.h>
#include <stdint.h>

#define NDET 8192
#define ROWCAP 128      // max stored edges per row (j>i). P(overflow) ~ 0 for this data.
#define BATCH 256
#define NBATCH (NDET / BATCH)   // 32

// ---------------- ws layout (bytes) ----------------
// 0        u32    cnt  [8192]     32768
// 32768    u32    alab [8192]     32768
// 65536    u16    sched[8192]     16384
// 81920    int    depth[32]         128
// 131072   u16    edges[8192][128] 2097152   (total 2228224 B)

// Extract edge e (compile-time constant after unroll) from the two uint4 regs.
#define EW(e) ((e) < 8 ? (((e) >> 1) == 0 ? pa.x : ((e) >> 1) == 1 ? pa.y : ((e) >> 1) == 2 ? pa.z : pa.w) \
                       : ((((e) - 8) >> 1) == 0 ? pb.x : (((e) - 8) >> 1) == 1 ? pb.y : (((e) - 8) >> 1) == 2 ? pb.z : pb.w))
#define EDGE(e) ((int)((EW(e) >> (((e) & 1) * 16)) & 0xFFFFu))

// Corner-form + area computed on the fly from raw cxcywh (bit-identical to the
// reference expressions; contract off so no FMA fusion changes rounding).
__device__ __forceinline__ void box_corners(const float4 b, float& x1, float& y1,
                                            float& x2, float& y2, float& ar) {
  #pragma clang fp contract(off)
  x1 = b.x - 0.5f * b.z; y1 = b.y - 0.5f * b.w;
  x2 = b.x + 0.5f * b.z; y2 = b.y + 0.5f * b.w;
  ar = (x2 - x1) * (y2 - y1);
}

// One wave handles rows (w) and (8191-w): balanced upper-triangle scan.
__global__ __launch_bounds__(256) void k_edges(const float4* __restrict__ bb,
    uint32_t* __restrict__ cnt, uint16_t* __restrict__ edges) {
  #pragma clang fp contract(off)
  int wid  = (blockIdx.x * 256 + threadIdx.x) >> 6;   // 0..4095
  int lane = threadIdx.x & 63;
  for (int half = 0; half < 2; ++half) {
    int r = (half == 0) ? wid : (NDET - 1 - wid);
    float ix1, iy1, ix2, iy2, ai;
    box_corners(bb[r], ix1, iy1, ix2, iy2, ai);
    uint16_t* erow = edges + (size_t)r * ROWCAP;
    int cnt_total = 0;
    for (int jc = (r + 1) >> 6; jc < NDET / 64; ++jc) {
      int j = (jc << 6) + lane;
      bool pred = false;
      if (j > r) {
        float jx1, jy1, jx2, jy2, aj;
        box_corners(bb[j], jx1, jy1, jx2, jy2, aj);
        float ltx = fmaxf(ix1, jx1), lty = fmaxf(iy1, jy1);
        float rbx = fminf(ix2, jx2), rby = fminf(iy2, jy2);
        float iw = fmaxf(rbx - ltx, 0.0f), ih = fmaxf(rby - lty, 0.0f);
        float inter = iw * ih;
        float uni = ai + aj - inter;     // > 0 always (w,h >= 10)
        float iou = inter / uni;         // IEEE div, matches reference
        pred = iou > 0.1f;
      }
      unsigned long long m = __ballot(pred);
      if (pred) {
        int pos = cnt_total + __popcll(m & ((1ull << lane) - 1ull));
        if (pos < ROWCAP) erow[pos] = (uint16_t)j;
      }
      cnt_total += __popcll(m);
    }
    if (lane == 0) cnt[r] = (uint32_t)min(cnt_total, ROWCAP);
  }
}

// Static conflict scheduling: one block per batch of 256 consecutive rows.
// Epoch-keyed claims (newer round -> smaller key), >=1 retire/round => k<=256.
__global__ __launch_bounds__(256) void k_sched(const uint16_t* __restrict__ edges,
    const uint32_t* __restrict__ cnt, uint16_t* __restrict__ sched,
    int* __restrict__ depth) {
  __shared__ uint32_t claim[NDET];     // 32 KB
  __shared__ int nleft;
  const int t = threadIdx.x;
  const int r = (blockIdx.x << 8) + t;
  {
    uint4* c4 = reinterpret_cast<uint4*>(claim);
    uint4 ff = make_uint4(0xFFFFFFFFu, 0xFFFFFFFFu, 0xFFFFFFFFu, 0xFFFFFFFFu);
    for (int v = t; v < NDET / 4; v += 256) c4[v] = ff;
  }
  const uint16_t* ep = edges + (size_t)r * ROWCAP;
  uint4 pa = *reinterpret_cast<const uint4*>(ep);
  uint4 pb = *reinterpret_cast<const uint4*>(ep + 8);
  uint32_t deg = cnt[r];
  int js[16];
  #pragma unroll
  for (int e = 0; e < 16; ++e) js[e] = EDGE(e);
  if (t == 0) nleft = 0;
  __syncthreads();
  bool done = (deg == 0u);             // zero-deg rows are exact no-ops, round 0
  if (!done) atomicAdd(&nleft, 1);
  uint32_t myround = 0u;
  int k = 0;
  __syncthreads();                     // nleft final; uniform reads below

  while (nleft > 0) {                  // uniform (read after barrier each iter)
    ++k;
    const uint32_t key = ((uint32_t)(600 - k) << 9) | (uint32_t)t;  // newer round -> smaller
    if (!done) {
      atomicMin(&claim[r], key);
      #pragma unroll
      for (int e = 0; e < 16; ++e)
        if (e < (int)deg) atomicMin(&claim[js[e]], key);
      if (deg > 16u)
        for (int e = 16; e < (int)deg; ++e) atomicMin(&claim[(int)ep[e]], key);
    }
    __syncthreads();
    if (!done) {
      uint32_t cl[16];
      #pragma unroll
      for (int e = 0; e < 16; ++e)
        cl[e] = (e < (int)deg) ? claim[js[e]] : key;   // independent reads, one wait
      bool ready = (claim[r] == key);
      #pragma unroll
      for (int e = 0; e < 16; ++e)
        if (cl[e] != key) ready = false;
      if (ready && deg > 16u)
        for (int e = 16; ready && e < (int)deg; ++e)
          if (claim[(int)ep[e]] != key) ready = false;
      if (ready) { myround = (uint32_t)k; done = true; atomicSub(&nleft, 1); }
    }
    __syncthreads();                   // retires visible; round-k keys now stale
  }
  sched[r] = (uint16_t)myround;
  if (t == 0) depth[blockIdx.x] = k;
}

// Multi-wave sequential-semantics executor: 32 batches of 256 rows in order;
// within a batch, rows execute at their precomputed round (disjoint per round).
// Row body = 3 phases (read-all / reg prefix-min / write-all): neighbors are
// strictly ascending => distinct, and the reference reads pre-row values, so
// this is exact and avoids per-edge LDS RAW round-trip serialization.
__global__ __launch_bounds__(256) void k_scan(const uint16_t* __restrict__ edges,
    const uint32_t* __restrict__ cnt, const uint16_t* __restrict__ sched,
    const int* __restrict__ depth, uint32_t* __restrict__ alab) {
  __shared__ uint16_t a[NDET];         // 16 KB labels
  const int t = threadIdx.x;
  for (int v = t; v < NDET; v += 256) a[v] = (uint16_t)v;

  // prefetch batch 0 (one row per thread)
  const uint16_t* ep = edges + (size_t)t * ROWCAP;
  uint4 pa = *reinterpret_cast<const uint4*>(ep);
  uint4 pb = *reinterpret_cast<const uint4*>(ep + 8);
  uint32_t deg = cnt[t];
  uint32_t rnd = sched[t];
  int dep = depth[0];
  __syncthreads();

  for (int b = 0; b < NBATCH; ++b) {
    const int r = (b << 8) + t;
    uint4 pan = make_uint4(0, 0, 0, 0), pbn = make_uint4(0, 0, 0, 0);
    uint32_t degn = 0u, rndn = 0u;
    int depn = 0;
    if (b < NBATCH - 1) {              // prefetch next batch; waits land after rounds
      const uint16_t* en = edges + (size_t)(r + BATCH) * ROWCAP;
      pan = *reinterpret_cast<const uint4*>(en);
      pbn = *reinterpret_cast<const uint4*>(en + 8);
      degn = cnt[r + BATCH];
      rndn = sched[r + BATCH];
      depn = depth[b + 1];
    }
    for (int k = 1; k <= dep; ++k) {   // uniform loop; no ballot
      if (rnd == (uint32_t)k) {
        int js[16], ls[16];
        #pragma unroll
        for (int e = 0; e < 16; ++e) js[e] = EDGE(e);
        #pragma unroll
        for (int e = 0; e < 16; ++e)   // phase 1: independent reads, one wait
          ls[e] = (e < (int)deg) ? (int)a[js[e]] : 0x7FFFFFFF;
        int cur = (int)a[r];
        #pragma unroll
        for (int e = 0; e < 16; ++e) { // phase 2: register prefix-min
          if (ls[e] < cur) cur = ls[e];
          ls[e] = cur;
        }
        #pragma unroll
        for (int e = 0; e < 16; ++e)   // phase 3: independent writes
          if (e < (int)deg) a[js[e]] = (uint16_t)ls[e];
        if (deg > 16u) {               // rare tail: sequential exact
          for (int e = 16; e < (int)deg; ++e) {
            int j = (int)edges[(size_t)r * ROWCAP + e];
            int aj = (int)a[j];
            if (aj < cur) cur = aj;
            a[j] = (uint16_t)cur;
          }
        }
        a[r] = (uint16_t)cur;
      }
      __syncthreads();
    }
    pa = pan; pb = pbn; deg = degn; rnd = rndn; dep = depn;
  }

  __syncthreads();
  for (int v = t; v < NDET; v += 256) alab[v] = (uint32_t)a[v];
}

// Representative selection entirely in LDS (single block, 1024 threads).
// T1: per-label maxconf bits (conf in [0,1) => non-negative => bit order ==
// float order), later re-zeroed and reused as packed cnt | rank<<16.
// T2: g = min index among members with conf bits == maxconf (exact reference
// tie-break). For cnt==1 the single member IS g, so no minidx table needed.
__global__ __launch_bounds__(1024) void k_fold(const uint32_t* __restrict__ alab,
    const float* __restrict__ conf, int32_t* __restrict__ out) {
  __shared__ uint32_t T1[NDET];        // 32 KB
  __shared__ uint32_t T2[NDET];        // 32 KB
  const int t = threadIdx.x;
  for (int v = t; v < NDET; v += 1024) { T1[v] = 0u; T2[v] = 0xFFFFFFFFu; out[v] = 0; }
  __syncthreads();
  uint32_t L[8], cb[8];
  #pragma unroll
  for (int i = 0; i < 8; ++i) {        // phase A: maxconf per label
    int v = t + i * 1024;
    L[i]  = alab[v];
    cb[i] = __float_as_uint(conf[v]);
    atomicMax(&T1[L[i]], cb[i]);
  }
  __syncthreads();
  #pragma unroll
  for (int i = 0; i < 8; ++i) {        // phase B: g = min idx among argmax-conf
    int v = t + i * 1024;
    if (T1[L[i]] == cb[i]) atomicMin(&T2[L[i]], (uint32_t)v);
  }
  __syncthreads();
  for (int v = t; v < NDET; v += 1024) T1[v] = 0u;   // reuse T1 as cnt|rank
  __syncthreads();
  #pragma unroll
  for (int i = 0; i < 8; ++i) {        // phase C: cnt (lo16) + rank (hi16)
    int v = t + i * 1024;
    atomicAdd(&T1[L[i]], 1u + (((uint32_t)v < T2[L[i]]) ? 0x10000u : 0u));
  }
  __syncthreads();
  for (int Lv = t; Lv < NDET; Lv += 1024) {          // phase D: emit mask
    uint32_t cr = T1[Lv];
    uint32_t c  = cr & 0xFFFFu;
    if (c > 0u) {
      uint32_t idx = (c == 1u) ? T2[Lv] : (cr >> 16);
      out[idx] = 1;                    // idx < NDET always
    }
  }
}

extern "C" void kernel_launch(void* const* d_in, const int* in_sizes, int n_in,
                              void* d_out, int out_size, void* d_ws, size_t ws_size,
                              hipStream_t stream) {
  const float4* bb  = (const float4*)d_in[0];
  const float* conf = (const float*)d_in[1];
  char* ws = (char*)d_ws;
  uint32_t* cnt   = (uint32_t*)(ws + 0);
  uint32_t* alab  = (uint32_t*)(ws + 32768);
  uint16_t* sched = (uint16_t*)(ws + 65536);
  int*      depth = (int*)(ws + 81920);
  uint16_t* edges = (uint16_t*)(ws + 131072);
  int32_t* out = (int32_t*)d_out;

  hipLaunchKernelGGL(k_edges, dim3(1024),   dim3(256),  0, stream, bb, cnt, edges);
  hipLaunchKernelGGL(k_sched, dim3(NBATCH), dim3(256),  0, stream, edges, cnt, sched, depth);
  hipLaunchKernelGGL(k_scan,  dim3(1),      dim3(256),  0, stream, edges, cnt, sched, depth, alab);
  hipLaunchKernelGGL(k_fold,  dim3(1),      dim3(1024), 0, stream, alab, conf, out);
}